// Round 4
// baseline (331.406 us; speedup 1.0000x reference)
//
#include <hip/hip_runtime.h>
#include <hip/hip_bf16.h>

#define B_ 8
#define S_ 2048
#define E_ 1024
#define D_ 64

typedef short short8 __attribute__((ext_vector_type(8)));
typedef float floatx4 __attribute__((ext_vector_type(4)));

static __device__ __forceinline__ short bf16_bits(float f) {
    __hip_bfloat16 h = __float2bfloat16(f);
    return *reinterpret_cast<short*>(&h);
}
static __device__ __forceinline__ float bits_to_f(short s) {
    __hip_bfloat16 h = *reinterpret_cast<__hip_bfloat16*>(&s);
    return __bfloat162float(h);
}
static __device__ __forceinline__ void split8(const float* __restrict__ p,
                                              short8& hi, short8& lo) {
    #pragma unroll
    for (int j = 0; j < 8; j++) {
        float f = p[j];
        short h = bf16_bits(f);
        hi[j] = h;
        lo[j] = bf16_bits(f - bits_to_f(h));
    }
}

// ---------------- QKV projection (fp32 in, hi/lo-compensated bf16 MFMA)
__global__ __launch_bounds__(256) void qkv_kernel(
    const float* __restrict__ x,
    const float* __restrict__ Wq, const float* __restrict__ bq,
    const float* __restrict__ Wk, const float* __restrict__ bk,
    const float* __restrict__ Wv, const float* __restrict__ bv,
    float* __restrict__ Qws, float* __restrict__ Kws, __hip_bfloat16* __restrict__ Vws)
{
    const int tid  = threadIdx.x;
    const int wave = tid >> 6;
    const int lane = tid & 63;
    const int l16  = lane & 15;
    const int quad = lane >> 4;
    const int arow = blockIdx.x * 64 + wave * 16 + l16;   // A row (m = l16)

    floatx4 acc[3][4];
    #pragma unroll
    for (int m = 0; m < 3; m++)
        #pragma unroll
        for (int nb = 0; nb < 4; nb++) acc[m][nb] = (floatx4){0.f,0.f,0.f,0.f};

    const float* Ws[3] = {Wq, Wk, Wv};

    for (int e0 = 0; e0 < E_; e0 += 32) {
        short8 ahi, alo;
        split8(x + (size_t)arow * E_ + e0 + quad * 8, ahi, alo);
        #pragma unroll
        for (int m = 0; m < 3; m++) {
            #pragma unroll
            for (int nb = 0; nb < 4; nb++) {
                short8 bhi, blo;
                split8(Ws[m] + (size_t)(nb * 16 + l16) * E_ + e0 + quad * 8, bhi, blo);
                acc[m][nb] = __builtin_amdgcn_mfma_f32_16x16x32_bf16(alo, bhi, acc[m][nb], 0, 0, 0);
                acc[m][nb] = __builtin_amdgcn_mfma_f32_16x16x32_bf16(ahi, blo, acc[m][nb], 0, 0, 0);
                acc[m][nb] = __builtin_amdgcn_mfma_f32_16x16x32_bf16(ahi, bhi, acc[m][nb], 0, 0, 0);
            }
        }
    }

    const int rowbase = blockIdx.x * 64 + wave * 16 + quad * 4;
    #pragma unroll
    for (int nb = 0; nb < 4; nb++) {
        const int d = nb * 16 + l16;
        const float bqv = bq[d];
        const float bkv = bk[d];
        const float bvv = bv[d];
        #pragma unroll
        for (int r = 0; r < 4; r++) {
            const size_t rr = (size_t)(rowbase + r);
            Qws[rr * D_ + d] = acc[0][nb][r] + bqv;
            Kws[rr * D_ + d] = acc[1][nb][r] + bkv;
            Vws[rr * D_ + d] = __float2bfloat16(acc[2][nb][r] + bvv);
        }
    }
}

// ---------------- Mask prep: 3-way dtype detection (int32 / uint8 / float32)
__global__ __launch_bounds__(256) void mask_prep(const void* __restrict__ mask_raw,
                                                 float* __restrict__ maskf)
{
    __shared__ unsigned int red[256];
    const unsigned int* w = (const unsigned int*)mask_raw;
    unsigned int local = 0;
    for (int i = threadIdx.x; i < 4096; i += 256) local |= w[i];
    red[threadIdx.x] = local;
    __syncthreads();
    for (int s = 128; s > 0; s >>= 1) {
        if (threadIdx.x < s) red[threadIdx.x] |= red[threadIdx.x + s];
        __syncthreads();
    }
    const unsigned int ov = red[0];
    const bool is_u8 = (ov > 1u) && ((ov >> 24) <= 1u);
    const int i = blockIdx.x * 256 + threadIdx.x;
    int v;
    if (ov == 0u)      v = 0;
    else if (is_u8)    v = (int)((const unsigned char*)mask_raw)[i];
    else               v = (((const unsigned int*)mask_raw)[i] != 0u);
    maskf[i] = v ? -1e30f : 0.0f;
}

// ---------------- Flash attention: 64 q-rows/block, 16/wave; key tiles of 64
__global__ __launch_bounds__(256) void attn_kernel(
    const float* __restrict__ Qws, const float* __restrict__ Kws,
    const __hip_bfloat16* __restrict__ Vws, const float* __restrict__ maskf,
    float* __restrict__ out)
{
    __shared__ alignas(16) short Khi[64][72];
    __shared__ alignas(16) short Klo[64][72];
    __shared__ alignas(16) short Vt [64][72];
    __shared__ alignas(16) short Pl [4][16][72];
    __shared__ float mk[64];

    const int tid  = threadIdx.x;
    const int wave = tid >> 6;
    const int lane = tid & 63;
    const int l16  = lane & 15;
    const int quad = lane >> 4;
    const int b    = blockIdx.x >> 5;
    const int qt   = blockIdx.x & 31;
    const int qrow = qt * 64 + wave * 16;

    short8 qhi[2], qlo[2];
    {
        const float* qp = Qws + ((size_t)b * S_ + qrow + l16) * D_;
        #pragma unroll
        for (int dc = 0; dc < 2; dc++) {
            #pragma unroll
            for (int j = 0; j < 8; j++) {
                float f = qp[dc * 32 + quad * 8 + j] * 0.125f;
                short h = bf16_bits(f);
                qhi[dc][j] = h;
                qlo[dc][j] = bf16_bits(f - bits_to_f(h));
            }
        }
    }

    float m_r[4], l_r[4];
    floatx4 O[4];
    #pragma unroll
    for (int r = 0; r < 4; r++) { m_r[r] = -1e30f; l_r[r] = 0.f; }
    #pragma unroll
    for (int ob = 0; ob < 4; ob++) O[ob] = (floatx4){0.f,0.f,0.f,0.f};

    for (int kt = 0; kt < S_; kt += 64) {
        __syncthreads();
        {
            const int krow = tid >> 2;
            const int dc4  = (tid & 3) * 16;
            const float* kp = Kws + ((size_t)b * S_ + kt + krow) * D_ + dc4;
            #pragma unroll
            for (int j = 0; j < 16; j++) {
                float f = kp[j];
                short h = bf16_bits(f);
                Khi[krow][dc4 + j] = h;
                Klo[krow][dc4 + j] = bf16_bits(f - bits_to_f(h));
            }
            const __hip_bfloat16* vp = Vws + ((size_t)b * S_ + kt + krow) * D_ + dc4;
            #pragma unroll
            for (int j = 0; j < 16; j++)
                Vt[dc4 + j][krow] = *reinterpret_cast<const short*>(vp + j);
            if (tid < 64) mk[tid] = maskf[(size_t)b * S_ + kt + tid];
        }
        __syncthreads();

        floatx4 sc[4];
        #pragma unroll
        for (int kb = 0; kb < 4; kb++) {
            floatx4 a = (floatx4){0.f,0.f,0.f,0.f};
            #pragma unroll
            for (int dc = 0; dc < 2; dc++) {
                short8 khf = *reinterpret_cast<const short8*>(&Khi[kb*16 + l16][dc*32 + quad*8]);
                short8 klf = *reinterpret_cast<const short8*>(&Klo[kb*16 + l16][dc*32 + quad*8]);
                a = __builtin_amdgcn_mfma_f32_16x16x32_bf16(qlo[dc], khf, a, 0, 0, 0);
                a = __builtin_amdgcn_mfma_f32_16x16x32_bf16(qhi[dc], klf, a, 0, 0, 0);
                a = __builtin_amdgcn_mfma_f32_16x16x32_bf16(qhi[dc], khf, a, 0, 0, 0);
            }
            sc[kb] = a;
        }
        #pragma unroll
        for (int kb = 0; kb < 4; kb++) {
            const float madd = mk[kb * 16 + l16];
            #pragma unroll
            for (int r = 0; r < 4; r++) sc[kb][r] += madd;
        }

        float p[4][4];
        #pragma unroll
        for (int r = 0; r < 4; r++) {
            float mx = fmaxf(fmaxf(sc[0][r], sc[1][r]), fmaxf(sc[2][r], sc[3][r]));
            #pragma unroll
            for (int off = 1; off < 16; off <<= 1)
                mx = fmaxf(mx, __shfl_xor(mx, off, 64));
            const float mnew  = fmaxf(fmaxf(m_r[r], mx), -1e29f);
            const float alpha = __expf(m_r[r] - mnew);
            float sum = 0.f;
            #pragma unroll
            for (int kb = 0; kb < 4; kb++) {
                float pe = __expf(sc[kb][r] - mnew);
                p[kb][r] = pe;
                sum += pe;
            }
            #pragma unroll
            for (int off = 1; off < 16; off <<= 1)
                sum += __shfl_xor(sum, off, 64);
            l_r[r] = l_r[r] * alpha + sum;
            m_r[r] = mnew;
            #pragma unroll
            for (int ob = 0; ob < 4; ob++) O[ob][r] *= alpha;
        }

        #pragma unroll
        for (int kb = 0; kb < 4; kb++)
            #pragma unroll
            for (int r = 0; r < 4; r++)
                Pl[wave][quad * 4 + r][kb * 16 + l16] = bf16_bits(p[kb][r]);
        __syncthreads();

        short8 pf[2];
        #pragma unroll
        for (int kc = 0; kc < 2; kc++)
            pf[kc] = *reinterpret_cast<const short8*>(&Pl[wave][l16][kc*32 + quad*8]);
        #pragma unroll
        for (int ob = 0; ob < 4; ob++) {
            #pragma unroll
            for (int kc = 0; kc < 2; kc++) {
                short8 vf = *reinterpret_cast<const short8*>(&Vt[ob*16 + l16][kc*32 + quad*8]);
                O[ob] = __builtin_amdgcn_mfma_f32_16x16x32_bf16(pf[kc], vf, O[ob], 0, 0, 0);
            }
        }
    }

    // epilogue: out is FLOAT32 (reference output dtype)
    #pragma unroll
    for (int ob = 0; ob < 4; ob++) {
        #pragma unroll
        for (int r = 0; r < 4; r++) {
            const int q_g = qrow + quad * 4 + r;
            out[((size_t)b * S_ + q_g) * D_ + ob * 16 + l16] = O[ob][r] / l_r[r];
        }
    }
}

extern "C" void kernel_launch(void* const* d_in, const int* in_sizes, int n_in,
                              void* d_out, int out_size, void* d_ws, size_t ws_size,
                              hipStream_t stream) {
    const float* x  = (const float*)d_in[0];
    const float* Wq = (const float*)d_in[1];
    const float* bq = (const float*)d_in[2];
    const float* Wk = (const float*)d_in[3];
    const float* bk = (const float*)d_in[4];
    const float* Wv = (const float*)d_in[5];
    const float* bv = (const float*)d_in[6];
    const void* mask = d_in[7];

    char* ws = (char*)d_ws;
    const size_t nrows = (size_t)B_ * S_;                 // 16384
    float* Qws = (float*)ws;                              // 4 MB
    float* Kws = (float*)(ws + nrows * D_ * 4);           // 4 MB
    __hip_bfloat16* Vws = (__hip_bfloat16*)(ws + 2 * nrows * D_ * 4); // 2 MB
    float* maskf = (float*)(ws + 2 * nrows * D_ * 4 + nrows * D_ * 2);

    qkv_kernel<<<256, 256, 0, stream>>>(x, Wq, bq, Wk, bk, Wv, bv, Qws, Kws, Vws);
    mask_prep<<<64, 256, 0, stream>>>(mask, maskf);
    attn_kernel<<<256, 256, 0, stream>>>(Qws, Kws, Vws, maskf,
                                         (float*)d_out);
}

// Round 5
// 263.895 us; speedup vs baseline: 1.2558x; 1.2558x over previous
//
#include <hip/hip_runtime.h>
#include <hip/hip_bf16.h>

#define B_ 8
#define S_ 2048
#define E_ 1024
#define D_ 64

typedef short short8 __attribute__((ext_vector_type(8)));
typedef float floatx4 __attribute__((ext_vector_type(4)));

static __device__ __forceinline__ short bf16_bits(float f) {
    __hip_bfloat16 h = __float2bfloat16(f);
    return *reinterpret_cast<short*>(&h);
}
static __device__ __forceinline__ float bits_to_f(short s) {
    __hip_bfloat16 h = *reinterpret_cast<__hip_bfloat16*>(&s);
    return __bfloat162float(h);
}
static __device__ __forceinline__ void split8(const float* __restrict__ p,
                                              short8& hi, short8& lo) {
    #pragma unroll
    for (int j = 0; j < 8; j++) {
        float f = p[j];
        short h = bf16_bits(f);
        hi[j] = h;
        lo[j] = bf16_bits(f - bits_to_f(h));
    }
}

// ---------------- W pre-pack: fp32 W[3][64][1024] -> hi/lo bf16 fragments in
// exact MFMA B-fragment order. Entry (e0c,m,nb,quad,l16) = 32B {hi8,lo8}.
__global__ __launch_bounds__(256) void w_pack(
    const float* __restrict__ Wq, const float* __restrict__ Wk,
    const float* __restrict__ Wv, short8* __restrict__ Wpk8)
{
    const int t = blockIdx.x * 256 + threadIdx.x;       // 24576 total
    const int l16  = t & 15;
    const int quad = (t >> 4) & 3;
    const int nb   = (t >> 6) & 3;
    const int m    = (t >> 8) % 3;
    const int e0c  = (t >> 8) / 3;                      // 0..31
    const float* W = (m == 0) ? Wq : ((m == 1) ? Wk : Wv);
    short8 hi, lo;
    split8(W + (size_t)(nb * 16 + l16) * E_ + e0c * 32 + quad * 8, hi, lo);
    Wpk8[(size_t)t * 2]     = hi;
    Wpk8[(size_t)t * 2 + 1] = lo;
}

// ---------------- Mask prep: 3-way dtype detection (int32 / uint8 / float32)
__global__ __launch_bounds__(256) void mask_prep(const void* __restrict__ mask_raw,
                                                 float* __restrict__ maskf)
{
    __shared__ unsigned int red[256];
    const unsigned int* w = (const unsigned int*)mask_raw;
    unsigned int local = 0;
    for (int i = threadIdx.x; i < 4096; i += 256) local |= w[i];
    red[threadIdx.x] = local;
    __syncthreads();
    for (int s = 128; s > 0; s >>= 1) {
        if (threadIdx.x < s) red[threadIdx.x] |= red[threadIdx.x + s];
        __syncthreads();
    }
    const unsigned int ov = red[0];
    const bool is_u8 = (ov > 1u) && ((ov >> 24) <= 1u);
    const int i = blockIdx.x * 256 + threadIdx.x;
    int v;
    if (ov == 0u)      v = 0;
    else if (is_u8)    v = (int)((const unsigned char*)mask_raw)[i];
    else               v = (((const unsigned int*)mask_raw)[i] != 0u);
    maskf[i] = v ? -1e30f : 0.0f;
}

// ---------------- QKV projection: split-K=2, 32 rows/block, grid 512.
// Emits pre-packed Qhi/Qlo (x0.125), Khi/Klo, V^T bf16 planes.
__global__ __launch_bounds__(256, 2) void qkv_kernel(
    const float* __restrict__ x, const short8* __restrict__ Wpk8,
    const float* __restrict__ bq, const float* __restrict__ bk,
    const float* __restrict__ bv,
    short* __restrict__ Qhi, short* __restrict__ Qlo,
    short* __restrict__ Khi, short* __restrict__ Klo,
    short* __restrict__ Vt)
{
    __shared__ float red[2][64][48];
    const int tid  = threadIdx.x;
    const int wave = tid >> 6;
    const int lane = tid & 63;
    const int l16  = lane & 15;
    const int quad = lane >> 4;
    const int rowTile = wave & 1;      // which 16-row half of the 32-row block
    const int ksel    = wave >> 1;     // which K half
    const int arow = blockIdx.x * 32 + rowTile * 16 + l16;

    floatx4 acc[3][4];
    #pragma unroll
    for (int m = 0; m < 3; m++)
        #pragma unroll
        for (int nb = 0; nb < 4; nb++) acc[m][nb] = (floatx4){0.f,0.f,0.f,0.f};

    const int e0c_beg = ksel * 16;
    const size_t lbase = (size_t)quad * 16 + l16;
    for (int e0c = e0c_beg; e0c < e0c_beg + 16; ++e0c) {
        short8 ahi, alo;
        split8(x + (size_t)arow * E_ + e0c * 32 + quad * 8, ahi, alo);
        #pragma unroll
        for (int m = 0; m < 3; m++) {
            #pragma unroll
            for (int nb = 0; nb < 4; nb++) {
                const size_t ent = ((size_t)((e0c * 3 + m) * 4 + nb) * 64 + lbase) * 2;
                short8 bhi = Wpk8[ent];
                short8 blo = Wpk8[ent + 1];
                acc[m][nb] = __builtin_amdgcn_mfma_f32_16x16x32_bf16(alo, bhi, acc[m][nb], 0, 0, 0);
                acc[m][nb] = __builtin_amdgcn_mfma_f32_16x16x32_bf16(ahi, blo, acc[m][nb], 0, 0, 0);
                acc[m][nb] = __builtin_amdgcn_mfma_f32_16x16x32_bf16(ahi, bhi, acc[m][nb], 0, 0, 0);
            }
        }
    }

    if (wave >= 2) {
        float* dst = &red[wave - 2][lane][0];
        #pragma unroll
        for (int m = 0; m < 3; m++)
            #pragma unroll
            for (int nb = 0; nb < 4; nb++)
                #pragma unroll
                for (int r = 0; r < 4; r++)
                    dst[(m * 4 + nb) * 4 + r] = acc[m][nb][r];
    }
    __syncthreads();
    if (wave < 2) {
        const float* src = &red[wave][lane][0];
        #pragma unroll
        for (int m = 0; m < 3; m++)
            #pragma unroll
            for (int nb = 0; nb < 4; nb++)
                #pragma unroll
                for (int r = 0; r < 4; r++)
                    acc[m][nb][r] += src[(m * 4 + nb) * 4 + r];

        const int rowbase = blockIdx.x * 32 + rowTile * 16 + quad * 4;
        #pragma unroll
        for (int nb = 0; nb < 4; nb++) {
            const int d = nb * 16 + l16;
            const float bqv = bq[d];
            const float bkv = bk[d];
            const float bvv = bv[d];
            #pragma unroll
            for (int r = 0; r < 4; r++) {
                const size_t row = (size_t)(rowbase + r);
                const float q = (acc[0][nb][r] + bqv) * 0.125f;
                const short qh = bf16_bits(q);
                Qhi[row * 64 + d] = qh;
                Qlo[row * 64 + d] = bf16_bits(q - bits_to_f(qh));
                const float k = acc[1][nb][r] + bkv;
                const short kh = bf16_bits(k);
                Khi[row * 64 + d] = kh;
                Klo[row * 64 + d] = bf16_bits(k - bits_to_f(kh));
                const float v = acc[2][nb][r] + bvv;
                Vt[((size_t)((row >> 11) * 64 + d)) * 2048 + (row & 2047)] = bf16_bits(v);
            }
        }
    }
}

// ---------------- Flash attention: 16 q-rows/block, 4-way key split, grid 1024.
// No staging, no in-loop barriers; all fragments direct from pre-packed planes.
__global__ __launch_bounds__(256, 3) void attn_kernel(
    const short* __restrict__ Qhi, const short* __restrict__ Qlo,
    const short* __restrict__ Khi, const short* __restrict__ Klo,
    const short* __restrict__ Vt, const float* __restrict__ maskf,
    float* __restrict__ out)
{
    __shared__ short Pl[4][16][72];     // per-wave P round-trip
    __shared__ float Osh[4][16][64];    // merge buffers
    __shared__ float msh[4][16], lsh[4][16];

    const int tid  = threadIdx.x;
    const int wave = tid >> 6;
    const int lane = tid & 63;
    const int l16  = lane & 15;
    const int quad = lane >> 4;
    const int b    = blockIdx.x >> 7;
    const int qt   = blockIdx.x & 127;
    const size_t qrow = (size_t)b * S_ + qt * 16;

    short8 qh[2], ql[2];
    #pragma unroll
    for (int dc = 0; dc < 2; dc++) {
        qh[dc] = *reinterpret_cast<const short8*>(Qhi + (qrow + l16) * 64 + dc * 32 + quad * 8);
        ql[dc] = *reinterpret_cast<const short8*>(Qlo + (qrow + l16) * 64 + dc * 32 + quad * 8);
    }

    float m_r[4], l_r[4];
    floatx4 O[4];
    #pragma unroll
    for (int r = 0; r < 4; r++) { m_r[r] = -1e30f; l_r[r] = 0.f; }
    #pragma unroll
    for (int ob = 0; ob < 4; ob++) O[ob] = (floatx4){0.f,0.f,0.f,0.f};

    const int kt0 = wave * 512;
    for (int kt = kt0; kt < kt0 + 512; kt += 64) {
        float mkv[4];
        floatx4 sc[4];
        #pragma unroll
        for (int kb = 0; kb < 4; kb++) {
            const size_t krow = (size_t)b * S_ + kt + kb * 16 + l16;
            mkv[kb] = maskf[krow];
            floatx4 a = (floatx4){0.f,0.f,0.f,0.f};
            #pragma unroll
            for (int dc = 0; dc < 2; dc++) {
                short8 kh = *reinterpret_cast<const short8*>(Khi + krow * 64 + dc * 32 + quad * 8);
                short8 kl = *reinterpret_cast<const short8*>(Klo + krow * 64 + dc * 32 + quad * 8);
                a = __builtin_amdgcn_mfma_f32_16x16x32_bf16(ql[dc], kh, a, 0, 0, 0);
                a = __builtin_amdgcn_mfma_f32_16x16x32_bf16(qh[dc], kl, a, 0, 0, 0);
                a = __builtin_amdgcn_mfma_f32_16x16x32_bf16(qh[dc], kh, a, 0, 0, 0);
            }
            sc[kb] = a;
        }
        #pragma unroll
        for (int kb = 0; kb < 4; kb++)
            #pragma unroll
            for (int r = 0; r < 4; r++) sc[kb][r] += mkv[kb];

        float p[4][4];
        #pragma unroll
        for (int r = 0; r < 4; r++) {
            float mx = fmaxf(fmaxf(sc[0][r], sc[1][r]), fmaxf(sc[2][r], sc[3][r]));
            #pragma unroll
            for (int off = 1; off < 16; off <<= 1)
                mx = fmaxf(mx, __shfl_xor(mx, off, 64));
            const float mnew  = fmaxf(fmaxf(m_r[r], mx), -1e29f);
            const float alpha = __expf(m_r[r] - mnew);
            float sum = 0.f;
            #pragma unroll
            for (int kb = 0; kb < 4; kb++) {
                float pe = __expf(sc[kb][r] - mnew);
                p[kb][r] = pe;
                sum += pe;
            }
            #pragma unroll
            for (int off = 1; off < 16; off <<= 1)
                sum += __shfl_xor(sum, off, 64);
            l_r[r] = l_r[r] * alpha + sum;
            m_r[r] = mnew;
            #pragma unroll
            for (int ob = 0; ob < 4; ob++) O[ob][r] *= alpha;
        }

        // P: C-layout -> A-layout via per-wave LDS (same-wave ds order, no barrier)
        #pragma unroll
        for (int kb = 0; kb < 4; kb++)
            #pragma unroll
            for (int r = 0; r < 4; r++)
                Pl[wave][quad * 4 + r][kb * 16 + l16] = bf16_bits(p[kb][r]);

        short8 pf[2];
        #pragma unroll
        for (int kc = 0; kc < 2; kc++)
            pf[kc] = *reinterpret_cast<const short8*>(&Pl[wave][l16][kc * 32 + quad * 8]);
        #pragma unroll
        for (int ob = 0; ob < 4; ob++) {
            #pragma unroll
            for (int kc = 0; kc < 2; kc++) {
                short8 vf = *reinterpret_cast<const short8*>(
                    Vt + ((size_t)(b * 64 + ob * 16 + l16)) * 2048 + kt + kc * 32 + quad * 8);
                O[ob] = __builtin_amdgcn_mfma_f32_16x16x32_bf16(pf[kc], vf, O[ob], 0, 0, 0);
            }
        }
    }

    // ---- merge the 4 key-splits (log-sum-exp combine)
    #pragma unroll
    for (int ob = 0; ob < 4; ob++)
        #pragma unroll
        for (int r = 0; r < 4; r++)
            Osh[wave][quad * 4 + r][ob * 16 + l16] = O[ob][r];
    if (l16 == 0) {
        #pragma unroll
        for (int r = 0; r < 4; r++) {
            msh[wave][quad * 4 + r] = m_r[r];
            lsh[wave][quad * 4 + r] = l_r[r];
        }
    }
    __syncthreads();

    const int col = wave * 16 + l16;
    #pragma unroll
    for (int r = 0; r < 4; r++) {
        const int row = quad * 4 + r;
        const float m0 = msh[0][row], m1 = msh[1][row], m2 = msh[2][row], m3 = msh[3][row];
        const float ms = fmaxf(fmaxf(m0, m1), fmaxf(m2, m3));
        const float w0 = __expf(m0 - ms), w1 = __expf(m1 - ms);
        const float w2 = __expf(m2 - ms), w3 = __expf(m3 - ms);
        const float lt = lsh[0][row] * w0 + lsh[1][row] * w1 +
                         lsh[2][row] * w2 + lsh[3][row] * w3;
        const float oa = Osh[0][row][col] * w0 + Osh[1][row][col] * w1 +
                         Osh[2][row][col] * w2 + Osh[3][row][col] * w3;
        out[(qrow + row) * 64 + col] = oa / lt;
    }
}

extern "C" void kernel_launch(void* const* d_in, const int* in_sizes, int n_in,
                              void* d_out, int out_size, void* d_ws, size_t ws_size,
                              hipStream_t stream) {
    const float* x  = (const float*)d_in[0];
    const float* Wq = (const float*)d_in[1];
    const float* bq = (const float*)d_in[2];
    const float* Wk = (const float*)d_in[3];
    const float* bk = (const float*)d_in[4];
    const float* Wv = (const float*)d_in[5];
    const float* bv = (const float*)d_in[6];
    const void* mask = d_in[7];

    char* ws = (char*)d_ws;
    const size_t PLANE = (size_t)B_ * S_ * D_;           // 1M shorts = 2MB
    short* Wpk = (short*)ws;                              // 768 KB
    short* Qhi = (short*)(ws + 768 * 1024);
    short* Qlo = Qhi + PLANE;
    short* Khi = Qlo + PLANE;
    short* Klo = Khi + PLANE;
    short* Vt  = Klo + PLANE;
    float* maskf = (float*)(Vt + PLANE);                  // 64 KB

    w_pack<<<96, 256, 0, stream>>>(Wq, Wk, Wv, (short8*)Wpk);
    mask_prep<<<64, 256, 0, stream>>>(mask, maskf);
    qkv_kernel<<<512, 256, 0, stream>>>(x, (const short8*)Wpk, bq, bk, bv,
                                        Qhi, Qlo, Khi, Klo, Vt);
    attn_kernel<<<1024, 256, 0, stream>>>(Qhi, Qlo, Khi, Klo, Vt, maskf,
                                          (float*)d_out);
}

// Round 6
// 225.631 us; speedup vs baseline: 1.4688x; 1.1696x over previous
//
#include <hip/hip_runtime.h>
#include <hip/hip_bf16.h>

#define B_ 8
#define S_ 2048
#define E_ 1024
#define D_ 64

typedef short short8 __attribute__((ext_vector_type(8)));
typedef short short4v __attribute__((ext_vector_type(4)));
typedef float floatx4 __attribute__((ext_vector_type(4)));

static __device__ __forceinline__ short bf16_bits(float f) {
    __hip_bfloat16 h = __float2bfloat16(f);
    return *reinterpret_cast<short*>(&h);
}
static __device__ __forceinline__ float bits_to_f(short s) {
    __hip_bfloat16 h = *reinterpret_cast<__hip_bfloat16*>(&s);
    return __bfloat162float(h);
}
static __device__ __forceinline__ void split8(const float* __restrict__ p,
                                              short8& hi, short8& lo) {
    #pragma unroll
    for (int j = 0; j < 8; j++) {
        float f = p[j];
        short h = bf16_bits(f);
        hi[j] = h;
        lo[j] = bf16_bits(f - bits_to_f(h));
    }
}

// ---------------- W pre-pack: fp32 W[3][64][1024] -> hi/lo bf16 B-fragments.
__global__ __launch_bounds__(256) void w_pack(
    const float* __restrict__ Wq, const float* __restrict__ Wk,
    const float* __restrict__ Wv, short8* __restrict__ Wpk8)
{
    const int t = blockIdx.x * 256 + threadIdx.x;       // 24576 total
    const int l16  = t & 15;
    const int quad = (t >> 4) & 3;
    const int nb   = (t >> 6) & 3;
    const int m    = (t >> 8) % 3;
    const int e0c  = (t >> 8) / 3;                      // 0..31
    const float* W = (m == 0) ? Wq : ((m == 1) ? Wk : Wv);
    short8 hi, lo;
    split8(W + (size_t)(nb * 16 + l16) * E_ + e0c * 32 + quad * 8, hi, lo);
    Wpk8[(size_t)t * 2]     = hi;
    Wpk8[(size_t)t * 2 + 1] = lo;
}

// ---------------- Mask prep: 3-way dtype detection (int32 / uint8 / float32)
__global__ __launch_bounds__(256) void mask_prep(const void* __restrict__ mask_raw,
                                                 float* __restrict__ maskf)
{
    __shared__ unsigned int red[256];
    const unsigned int* w = (const unsigned int*)mask_raw;
    unsigned int local = 0;
    for (int i = threadIdx.x; i < 4096; i += 256) local |= w[i];
    red[threadIdx.x] = local;
    __syncthreads();
    for (int s = 128; s > 0; s >>= 1) {
        if (threadIdx.x < s) red[threadIdx.x] |= red[threadIdx.x + s];
        __syncthreads();
    }
    const unsigned int ov = red[0];
    const bool is_u8 = (ov > 1u) && ((ov >> 24) <= 1u);
    const int i = blockIdx.x * 256 + threadIdx.x;
    int v;
    if (ov == 0u)      v = 0;
    else if (is_u8)    v = (int)((const unsigned char*)mask_raw)[i];
    else               v = (((const unsigned int*)mask_raw)[i] != 0u);
    maskf[i] = v ? -1e30f : 0.0f;
}

// ---------------- QKV projection: 16 rows/block, 4-way split-K, grid 1024.
__global__ __launch_bounds__(256, 4) void qkv_kernel(
    const float* __restrict__ x, const short8* __restrict__ Wpk8,
    const float* __restrict__ bq, const float* __restrict__ bk,
    const float* __restrict__ bv,
    short* __restrict__ Qhi, short* __restrict__ Qlo,
    short* __restrict__ Khi, short* __restrict__ Vt)
{
    __shared__ float4 red4[3][64][13];   // [src wave-1][lane][m*4+nb], pad 13
    const int tid  = threadIdx.x;
    const int wave = tid >> 6;           // = ksel 0..3
    const int lane = tid & 63;
    const int l16  = lane & 15;
    const int quad = lane >> 4;
    const int arow = blockIdx.x * 16 + l16;

    floatx4 acc[3][4];
    #pragma unroll
    for (int m = 0; m < 3; m++)
        #pragma unroll
        for (int nb = 0; nb < 4; nb++) acc[m][nb] = (floatx4){0.f,0.f,0.f,0.f};

    const size_t lbase = (size_t)quad * 16 + l16;
    const int e0c_beg = wave * 8;
    for (int e0c = e0c_beg; e0c < e0c_beg + 8; ++e0c) {
        short8 ahi, alo;
        split8(x + (size_t)arow * E_ + e0c * 32 + quad * 8, ahi, alo);
        #pragma unroll
        for (int m = 0; m < 3; m++) {
            #pragma unroll
            for (int nb = 0; nb < 4; nb++) {
                const size_t ent = ((size_t)((e0c * 3 + m) * 4 + nb) * 64 + lbase) * 2;
                short8 bhi = Wpk8[ent];
                short8 blo = Wpk8[ent + 1];
                acc[m][nb] = __builtin_amdgcn_mfma_f32_16x16x32_bf16(alo, bhi, acc[m][nb], 0, 0, 0);
                acc[m][nb] = __builtin_amdgcn_mfma_f32_16x16x32_bf16(ahi, blo, acc[m][nb], 0, 0, 0);
                acc[m][nb] = __builtin_amdgcn_mfma_f32_16x16x32_bf16(ahi, bhi, acc[m][nb], 0, 0, 0);
            }
        }
    }

    if (wave >= 1) {
        #pragma unroll
        for (int m = 0; m < 3; m++)
            #pragma unroll
            for (int nb = 0; nb < 4; nb++)
                red4[wave - 1][lane][m * 4 + nb] =
                    (float4){acc[m][nb][0], acc[m][nb][1], acc[m][nb][2], acc[m][nb][3]};
    }
    __syncthreads();
    if (wave == 0) {
        #pragma unroll
        for (int w = 0; w < 3; w++)
            #pragma unroll
            for (int m = 0; m < 3; m++)
                #pragma unroll
                for (int nb = 0; nb < 4; nb++) {
                    float4 t = red4[w][lane][m * 4 + nb];
                    acc[m][nb][0] += t.x; acc[m][nb][1] += t.y;
                    acc[m][nb][2] += t.z; acc[m][nb][3] += t.w;
                }

        const int rowbase = blockIdx.x * 16 + quad * 4;
        const int bch = rowbase >> 11;
        const int s0  = rowbase & 2047;
        #pragma unroll
        for (int nb = 0; nb < 4; nb++) {
            const int d = nb * 16 + l16;
            const float bqv = bq[d];
            const float bkv = bk[d];
            const float bvv = bv[d];
            short4v vpk;
            #pragma unroll
            for (int r = 0; r < 4; r++) {
                const size_t row = (size_t)(rowbase + r);
                const float q = (acc[0][nb][r] + bqv) * 0.125f;
                const short qhv = bf16_bits(q);
                Qhi[row * 64 + d] = qhv;
                Qlo[row * 64 + d] = bf16_bits(q - bits_to_f(qhv));
                Khi[row * 64 + d] = bf16_bits(acc[1][nb][r] + bkv);
                vpk[r] = bf16_bits(acc[2][nb][r] + bvv);
            }
            *reinterpret_cast<short4v*>(Vt + ((size_t)(bch * 64 + d)) * 2048 + s0) = vpk;
        }
    }
}

// ---------------- Flash attention (transposed): 16 q/block, 8-way key split,
// 512 threads, grid 1024. S^T = K.Q^T so softmax reduces in-lane + 2 shuffles.
union alignas(16) AttnLds {
    short PlT[8][16][72];                // per-wave P^T [q][key], 18.4 KB
    struct {
        float Osh[8][16][65];            // 33.3 KB (union: barrier-protected)
        float msh[8][16];
        float lsh[8][16];
    } mg;
};

__global__ __launch_bounds__(512, 6) void attn_kernel(
    const short* __restrict__ Qhi, const short* __restrict__ Qlo,
    const short* __restrict__ Khi, const short* __restrict__ Vt,
    const float* __restrict__ maskf, float* __restrict__ out)
{
    __shared__ AttnLds lds;
    const int tid  = threadIdx.x;
    const int wave = tid >> 6;          // 0..7
    const int lane = tid & 63;
    const int l16  = lane & 15;
    const int quad = lane >> 4;
    const int b    = blockIdx.x >> 7;
    const int qt   = blockIdx.x & 127;
    const size_t qbase  = (size_t)b * S_ + qt * 16;
    const size_t kplane = (size_t)b * S_;

    // Q fragments (B-operand layout: lane=query, k=d)
    short8 qh[2], ql[2];
    #pragma unroll
    for (int dc = 0; dc < 2; dc++) {
        qh[dc] = *reinterpret_cast<const short8*>(Qhi + (qbase + l16) * 64 + dc * 32 + quad * 8);
        ql[dc] = *reinterpret_cast<const short8*>(Qlo + (qbase + l16) * 64 + dc * 32 + quad * 8);
    }

    float m = -1e30f, l = 0.f;
    floatx4 O[4];
    #pragma unroll
    for (int ob = 0; ob < 4; ob++) O[ob] = (floatx4){0.f,0.f,0.f,0.f};

    const int kt0 = wave * 256;
    for (int kt = kt0; kt < kt0 + 256; kt += 64) {
        // S^T = K . Q^T ; C rows = keys (quad*4+r), cols = queries (l16)
        floatx4 sc[4];
        #pragma unroll
        for (int kb = 0; kb < 4; kb++) {
            floatx4 a = (floatx4){0.f,0.f,0.f,0.f};
            #pragma unroll
            for (int kc = 0; kc < 2; kc++) {
                short8 kf = *reinterpret_cast<const short8*>(
                    Khi + (kplane + kt + kb * 16 + l16) * 64 + kc * 32 + quad * 8);
                a = __builtin_amdgcn_mfma_f32_16x16x32_bf16(kf, qh[kc], a, 0, 0, 0);
                a = __builtin_amdgcn_mfma_f32_16x16x32_bf16(kf, ql[kc], a, 0, 0, 0);
            }
            sc[kb] = a;
        }
        #pragma unroll
        for (int kb = 0; kb < 4; kb++) {
            float4 mk4 = *reinterpret_cast<const float4*>(
                maskf + kplane + kt + kb * 16 + quad * 4);
            const float* mkp = reinterpret_cast<const float*>(&mk4);
            #pragma unroll
            for (int r = 0; r < 4; r++) sc[kb][r] += mkp[r];
        }

        // online softmax for query l16: in-lane tree + 2 cross-quad shuffles
        float mx = -1e30f;
        #pragma unroll
        for (int kb = 0; kb < 4; kb++)
            #pragma unroll
            for (int r = 0; r < 4; r++) mx = fmaxf(mx, sc[kb][r]);
        mx = fmaxf(mx, __shfl_xor(mx, 16, 64));
        mx = fmaxf(mx, __shfl_xor(mx, 32, 64));
        const float mnew  = fmaxf(fmaxf(m, mx), -1e29f);
        const float alpha = __expf(m - mnew);
        float ps = 0.f;
        #pragma unroll
        for (int kb = 0; kb < 4; kb++)
            #pragma unroll
            for (int r = 0; r < 4; r++) {
                const float pe = __expf(sc[kb][r] - mnew);
                sc[kb][r] = pe;
                ps += pe;
            }
        ps += __shfl_xor(ps, 16, 64);
        ps += __shfl_xor(ps, 32, 64);
        l = l * alpha + ps;
        m = mnew;
        #pragma unroll
        for (int ob = 0; ob < 4; ob++) O[ob] *= alpha;

        // P^T -> B-operand layout via per-wave LDS (no barrier needed)
        #pragma unroll
        for (int kb = 0; kb < 4; kb++)
            #pragma unroll
            for (int r = 0; r < 4; r++)
                lds.PlT[wave][l16][kb * 16 + quad * 4 + r] = bf16_bits(sc[kb][r]);

        short8 pf[2];
        #pragma unroll
        for (int kc = 0; kc < 2; kc++)
            pf[kc] = *reinterpret_cast<const short8*>(&lds.PlT[wave][l16][kc * 32 + quad * 8]);
        #pragma unroll
        for (int ob = 0; ob < 4; ob++) {
            #pragma unroll
            for (int kc = 0; kc < 2; kc++) {
                short8 vf = *reinterpret_cast<const short8*>(
                    Vt + ((size_t)(b * 64 + ob * 16 + l16)) * 2048 + kt + kc * 32 + quad * 8);
                O[ob] = __builtin_amdgcn_mfma_f32_16x16x32_bf16(vf, pf[kc], O[ob], 0, 0, 0);
            }
        }
    }

    __syncthreads();   // union transition: all waves done with PlT
    // deposit partials: O^T rows d=ob*16+quad*4+r, col q=l16
    #pragma unroll
    for (int ob = 0; ob < 4; ob++)
        #pragma unroll
        for (int r = 0; r < 4; r++)
            lds.mg.Osh[wave][l16][ob * 16 + quad * 4 + r] = O[ob][r];
    if (quad == 0) {
        lds.mg.msh[wave][l16] = m;
        lds.mg.lsh[wave][l16] = l;
    }
    __syncthreads();

    // merge 8 key-splits (LSE combine); one output element per thread x2
    #pragma unroll
    for (int part = 0; part < 2; part++) {
        const int idx = part * 512 + tid;
        const int q = idx >> 6;
        const int d = idx & 63;
        float ms = -1e30f;
        #pragma unroll
        for (int w = 0; w < 8; w++) ms = fmaxf(ms, lds.mg.msh[w][q]);
        float lt = 0.f, oa = 0.f;
        #pragma unroll
        for (int w = 0; w < 8; w++) {
            const float ww = __expf(lds.mg.msh[w][q] - ms);
            lt += lds.mg.lsh[w][q] * ww;
            oa += lds.mg.Osh[w][q][d] * ww;
        }
        out[(qbase + q) * 64 + d] = oa / lt;
    }
}

extern "C" void kernel_launch(void* const* d_in, const int* in_sizes, int n_in,
                              void* d_out, int out_size, void* d_ws, size_t ws_size,
                              hipStream_t stream) {
    const float* x  = (const float*)d_in[0];
    const float* Wq = (const float*)d_in[1];
    const float* bq = (const float*)d_in[2];
    const float* Wk = (const float*)d_in[3];
    const float* bk = (const float*)d_in[4];
    const float* Wv = (const float*)d_in[5];
    const float* bv = (const float*)d_in[6];
    const void* mask = d_in[7];

    char* ws = (char*)d_ws;
    const size_t PLANE = (size_t)B_ * S_ * D_;           // 1M shorts = 2MB
    short* Wpk = (short*)ws;                              // 768 KB
    short* Qhi = (short*)(ws + 768 * 1024);
    short* Qlo = Qhi + PLANE;
    short* Khi = Qlo + PLANE;
    short* Vt  = Khi + PLANE;
    float* maskf = (float*)(Vt + PLANE);                  // 64 KB

    w_pack<<<96, 256, 0, stream>>>(Wq, Wk, Wv, (short8*)Wpk);
    mask_prep<<<64, 256, 0, stream>>>(mask, maskf);
    qkv_kernel<<<1024, 256, 0, stream>>>(x, (const short8*)Wpk, bq, bk, bv,
                                         Qhi, Qlo, Khi, Vt);
    attn_kernel<<<1024, 512, 0, stream>>>(Qhi, Qlo, Khi, Vt, maskf,
                                          (float*)d_out);
}

// Round 7
// 223.088 us; speedup vs baseline: 1.4855x; 1.0114x over previous
//
#include <hip/hip_runtime.h>
#include <hip/hip_bf16.h>

#define B_ 8
#define S_ 2048
#define E_ 1024
#define D_ 64
#define VT_STRIDE 2112   // 2048 + 64: breaks 4KB channel camping

typedef short short8 __attribute__((ext_vector_type(8)));
typedef short short4v __attribute__((ext_vector_type(4)));
typedef float floatx4 __attribute__((ext_vector_type(4)));

static __device__ __forceinline__ short bf16_bits(float f) {
    __hip_bfloat16 h = __float2bfloat16(f);
    return *reinterpret_cast<short*>(&h);
}
static __device__ __forceinline__ float bits_to_f(short s) {
    __hip_bfloat16 h = *reinterpret_cast<__hip_bfloat16*>(&s);
    return __bfloat162float(h);
}
static __device__ __forceinline__ void split8(const float* __restrict__ p,
                                              short8& hi, short8& lo) {
    #pragma unroll
    for (int j = 0; j < 8; j++) {
        float f = p[j];
        short h = bf16_bits(f);
        hi[j] = h;
        lo[j] = bf16_bits(f - bits_to_f(h));
    }
}

// ---------------- W pre-pack: fp32 W[3][64][1024] -> hi/lo bf16 B-fragments.
__global__ __launch_bounds__(256) void w_pack(
    const float* __restrict__ Wq, const float* __restrict__ Wk,
    const float* __restrict__ Wv, short8* __restrict__ Wpk8)
{
    const int t = blockIdx.x * 256 + threadIdx.x;       // 24576 total
    const int l16  = t & 15;
    const int quad = (t >> 4) & 3;
    const int nb   = (t >> 6) & 3;
    const int m    = (t >> 8) % 3;
    const int e0c  = (t >> 8) / 3;                      // 0..31
    const float* W = (m == 0) ? Wq : ((m == 1) ? Wk : Wv);
    short8 hi, lo;
    split8(W + (size_t)(nb * 16 + l16) * E_ + e0c * 32 + quad * 8, hi, lo);
    Wpk8[(size_t)t * 2]     = hi;
    Wpk8[(size_t)t * 2 + 1] = lo;
}

// ---------------- Mask prep: 3-way dtype detection (int32 / uint8 / float32)
__global__ __launch_bounds__(256) void mask_prep(const void* __restrict__ mask_raw,
                                                 float* __restrict__ maskf)
{
    __shared__ unsigned int red[256];
    const unsigned int* w = (const unsigned int*)mask_raw;
    unsigned int local = 0;
    for (int i = threadIdx.x; i < 4096; i += 256) local |= w[i];
    red[threadIdx.x] = local;
    __syncthreads();
    for (int s = 128; s > 0; s >>= 1) {
        if (threadIdx.x < s) red[threadIdx.x] |= red[threadIdx.x + s];
        __syncthreads();
    }
    const unsigned int ov = red[0];
    const bool is_u8 = (ov > 1u) && ((ov >> 24) <= 1u);
    const int i = blockIdx.x * 256 + threadIdx.x;
    int v;
    if (ov == 0u)      v = 0;
    else if (is_u8)    v = (int)((const unsigned char*)mask_raw)[i];
    else               v = (((const unsigned int*)mask_raw)[i] != 0u);
    maskf[i] = v ? -1e30f : 0.0f;
}

// ---------------- QKV: 32 rows/block, full-K per wave (no reduction),
// wave = one nb (16 d-cols) x 2 row-tiles. Grid 512. W pairs loaded once
// per wave serve 32 rows; 6-deep load batch per e0c for MLP.
__global__ __launch_bounds__(256, 4) void qkv_kernel(
    const float* __restrict__ x, const short8* __restrict__ Wpk8,
    const float* __restrict__ bq, const float* __restrict__ bk,
    const float* __restrict__ bv,
    short* __restrict__ Qhi, short* __restrict__ Qlo,
    short* __restrict__ Khi, short* __restrict__ Vt)
{
    const int tid  = threadIdx.x;
    const int nb   = tid >> 6;          // wave = nb 0..3
    const int lane = tid & 63;
    const int l16  = lane & 15;
    const int quad = lane >> 4;
    const int row0 = blockIdx.x * 32;

    floatx4 acc[3][2];
    #pragma unroll
    for (int m = 0; m < 3; m++)
        #pragma unroll
        for (int rt = 0; rt < 2; rt++) acc[m][rt] = (floatx4){0.f,0.f,0.f,0.f};

    const size_t lbase = (size_t)quad * 16 + l16;

    for (int e0c = 0; e0c < 32; ++e0c) {
        // batch-issue all 6 W fragment loads (MLP)
        short8 wh[3], wl[3];
        #pragma unroll
        for (int m = 0; m < 3; m++) {
            const size_t ent = ((size_t)((e0c * 3 + m) * 4 + nb) * 64 + lbase) * 2;
            wh[m] = Wpk8[ent];
            wl[m] = Wpk8[ent + 1];
        }
        // x splits for the 2 row-tiles
        short8 ah[2], al[2];
        #pragma unroll
        for (int rt = 0; rt < 2; rt++)
            split8(x + (size_t)(row0 + rt * 16 + l16) * E_ + e0c * 32 + quad * 8,
                   ah[rt], al[rt]);
        #pragma unroll
        for (int m = 0; m < 3; m++)
            #pragma unroll
            for (int rt = 0; rt < 2; rt++) {
                acc[m][rt] = __builtin_amdgcn_mfma_f32_16x16x32_bf16(al[rt], wh[m], acc[m][rt], 0, 0, 0);
                acc[m][rt] = __builtin_amdgcn_mfma_f32_16x16x32_bf16(ah[rt], wl[m], acc[m][rt], 0, 0, 0);
                acc[m][rt] = __builtin_amdgcn_mfma_f32_16x16x32_bf16(ah[rt], wh[m], acc[m][rt], 0, 0, 0);
            }
    }

    // epilogue: C rows = row0 + rt*16 + quad*4 + r, col d = nb*16 + l16
    const int d = nb * 16 + l16;
    const float bqv = bq[d];
    const float bkv = bk[d];
    const float bvv = bv[d];
    const int bch = row0 >> 11;
    #pragma unroll
    for (int rt = 0; rt < 2; rt++) {
        const int rowbase = row0 + rt * 16 + quad * 4;
        short4v vpk;
        #pragma unroll
        for (int r = 0; r < 4; r++) {
            const size_t row = (size_t)(rowbase + r);
            const float q = (acc[0][rt][r] + bqv) * 0.125f;
            const short qhv = bf16_bits(q);
            Qhi[row * 64 + d] = qhv;
            Qlo[row * 64 + d] = bf16_bits(q - bits_to_f(qhv));
            Khi[row * 64 + d] = bf16_bits(acc[1][rt][r] + bkv);
            vpk[r] = bf16_bits(acc[2][rt][r] + bvv);
        }
        const int s0 = (rowbase & 2047);
        *reinterpret_cast<short4v*>(Vt + ((size_t)(bch * 64 + d)) * VT_STRIDE + s0) = vpk;
    }
}

// ---------------- Flash attention (transposed): 16 q/block, 4-way key split,
// 256 threads, grid 1024. Pipelined loads: V issued at tile start, K batch
// before QK and refilled during softmax.
union alignas(16) AttnLds {
    short PlT[4][16][72];               // per-wave P^T round-trip
    struct {
        float Osh[4][16][65];
        float msh[4][16], lsh[4][16];
    } mg;
};

__global__ __launch_bounds__(256, 3) void attn_kernel(
    const short* __restrict__ Qhi, const short* __restrict__ Qlo,
    const short* __restrict__ Khi, const short* __restrict__ Vt,
    const float* __restrict__ maskf, float* __restrict__ out)
{
    __shared__ AttnLds lds;
    const int tid  = threadIdx.x;
    const int wave = tid >> 6;          // 0..3
    const int lane = tid & 63;
    const int l16  = lane & 15;
    const int quad = lane >> 4;
    const int b    = blockIdx.x >> 7;
    const int qt   = blockIdx.x & 127;
    const size_t qbase  = (size_t)b * S_ + qt * 16;
    const size_t kplane = (size_t)b * S_;
    const short* Vb = Vt + (size_t)b * 64 * VT_STRIDE;

    short8 qh[2], ql[2];
    #pragma unroll
    for (int dc = 0; dc < 2; dc++) {
        qh[dc] = *reinterpret_cast<const short8*>(Qhi + (qbase + l16) * 64 + dc * 32 + quad * 8);
        ql[dc] = *reinterpret_cast<const short8*>(Qlo + (qbase + l16) * 64 + dc * 32 + quad * 8);
    }

    float m = -1e30f, l = 0.f;
    floatx4 O[4];
    #pragma unroll
    for (int ob = 0; ob < 4; ob++) O[ob] = (floatx4){0.f,0.f,0.f,0.f};

    const int kt0 = wave * 512;

    // preload K fragments for first tile (batch of 8 loads in flight)
    short8 kf[4][2];
    #pragma unroll
    for (int kb = 0; kb < 4; kb++)
        #pragma unroll
        for (int kc = 0; kc < 2; kc++)
            kf[kb][kc] = *reinterpret_cast<const short8*>(
                Khi + (kplane + kt0 + kb * 16 + l16) * 64 + kc * 32 + quad * 8);

    for (int t = 0; t < 8; ++t) {
        const int kt = kt0 + t * 64;

        // issue V loads now — consumed ~500 cycles later at PV
        short8 vf[4][2];
        #pragma unroll
        for (int ob = 0; ob < 4; ob++)
            #pragma unroll
            for (int kc = 0; kc < 2; kc++)
                vf[ob][kc] = *reinterpret_cast<const short8*>(
                    Vb + (size_t)(ob * 16 + l16) * VT_STRIDE + kt + kc * 32 + quad * 8);
        float4 mk4[4];
        #pragma unroll
        for (int kb = 0; kb < 4; kb++)
            mk4[kb] = *reinterpret_cast<const float4*>(
                maskf + kplane + kt + kb * 16 + quad * 4);

        // S^T = K . Q^T
        floatx4 sc[4];
        #pragma unroll
        for (int kb = 0; kb < 4; kb++) {
            floatx4 a = (floatx4){0.f,0.f,0.f,0.f};
            #pragma unroll
            for (int kc = 0; kc < 2; kc++) {
                a = __builtin_amdgcn_mfma_f32_16x16x32_bf16(kf[kb][kc], qh[kc], a, 0, 0, 0);
                a = __builtin_amdgcn_mfma_f32_16x16x32_bf16(kf[kb][kc], ql[kc], a, 0, 0, 0);
            }
            sc[kb] = a;
        }

        // refill K for next tile — in flight during softmax
        if (t < 7) {
            #pragma unroll
            for (int kb = 0; kb < 4; kb++)
                #pragma unroll
                for (int kc = 0; kc < 2; kc++)
                    kf[kb][kc] = *reinterpret_cast<const short8*>(
                        Khi + (kplane + kt + 64 + kb * 16 + l16) * 64 + kc * 32 + quad * 8);
        }

        #pragma unroll
        for (int kb = 0; kb < 4; kb++) {
            const float* mkp = reinterpret_cast<const float*>(&mk4[kb]);
            #pragma unroll
            for (int r = 0; r < 4; r++) sc[kb][r] += mkp[r];
        }

        // online softmax (query = l16): in-lane tree + 2 shuffles
        float mx = -1e30f;
        #pragma unroll
        for (int kb = 0; kb < 4; kb++)
            #pragma unroll
            for (int r = 0; r < 4; r++) mx = fmaxf(mx, sc[kb][r]);
        mx = fmaxf(mx, __shfl_xor(mx, 16, 64));
        mx = fmaxf(mx, __shfl_xor(mx, 32, 64));
        const float mnew  = fmaxf(fmaxf(m, mx), -1e29f);
        const float alpha = __expf(m - mnew);
        float ps = 0.f;
        #pragma unroll
        for (int kb = 0; kb < 4; kb++)
            #pragma unroll
            for (int r = 0; r < 4; r++) {
                const float pe = __expf(sc[kb][r] - mnew);
                sc[kb][r] = pe;
                ps += pe;
            }
        ps += __shfl_xor(ps, 16, 64);
        ps += __shfl_xor(ps, 32, 64);
        l = l * alpha + ps;
        m = mnew;
        #pragma unroll
        for (int ob = 0; ob < 4; ob++) O[ob] *= alpha;

        // P^T -> B-operand layout via per-wave LDS
        #pragma unroll
        for (int kb = 0; kb < 4; kb++)
            #pragma unroll
            for (int r = 0; r < 4; r++)
                lds.PlT[wave][l16][kb * 16 + quad * 4 + r] = bf16_bits(sc[kb][r]);

        short8 pf[2];
        #pragma unroll
        for (int kc = 0; kc < 2; kc++)
            pf[kc] = *reinterpret_cast<const short8*>(&lds.PlT[wave][l16][kc * 32 + quad * 8]);
        #pragma unroll
        for (int ob = 0; ob < 4; ob++)
            #pragma unroll
            for (int kc = 0; kc < 2; kc++)
                O[ob] = __builtin_amdgcn_mfma_f32_16x16x32_bf16(vf[ob][kc], pf[kc], O[ob], 0, 0, 0);
    }

    __syncthreads();   // union transition
    #pragma unroll
    for (int ob = 0; ob < 4; ob++)
        #pragma unroll
        for (int r = 0; r < 4; r++)
            lds.mg.Osh[wave][l16][ob * 16 + quad * 4 + r] = O[ob][r];
    if (quad == 0) {
        lds.mg.msh[wave][l16] = m;
        lds.mg.lsh[wave][l16] = l;
    }
    __syncthreads();

    // merge 4 key-splits (LSE combine); 4 outputs per thread
    #pragma unroll
    for (int part = 0; part < 4; part++) {
        const int idx = part * 256 + tid;
        const int q = idx >> 6;
        const int d = idx & 63;
        float ms = -1e30f;
        #pragma unroll
        for (int w = 0; w < 4; w++) ms = fmaxf(ms, lds.mg.msh[w][q]);
        float lt = 0.f, oa = 0.f;
        #pragma unroll
        for (int w = 0; w < 4; w++) {
            const float ww = __expf(lds.mg.msh[w][q] - ms);
            lt += lds.mg.lsh[w][q] * ww;
            oa += lds.mg.Osh[w][q][d] * ww;
        }
        out[(qbase + q) * 64 + d] = oa / lt;
    }
}

extern "C" void kernel_launch(void* const* d_in, const int* in_sizes, int n_in,
                              void* d_out, int out_size, void* d_ws, size_t ws_size,
                              hipStream_t stream) {
    const float* x  = (const float*)d_in[0];
    const float* Wq = (const float*)d_in[1];
    const float* bq = (const float*)d_in[2];
    const float* Wk = (const float*)d_in[3];
    const float* bk = (const float*)d_in[4];
    const float* Wv = (const float*)d_in[5];
    const float* bv = (const float*)d_in[6];
    const void* mask = d_in[7];

    char* ws = (char*)d_ws;
    const size_t PLANE = (size_t)B_ * S_ * D_;           // 1M shorts = 2MB
    short* Wpk = (short*)ws;                              // 768 KB
    short* Qhi = (short*)(ws + 768 * 1024);
    short* Qlo = Qhi + PLANE;
    short* Khi = Qlo + PLANE;
    short* Vt  = Khi + PLANE;                             // 512*2112 shorts
    float* maskf = (float*)(Vt + (size_t)512 * VT_STRIDE);

    w_pack<<<96, 256, 0, stream>>>(Wq, Wk, Wv, (short8*)Wpk);
    mask_prep<<<64, 256, 0, stream>>>(mask, maskf);
    qkv_kernel<<<512, 256, 0, stream>>>(x, (const short8*)Wpk, bq, bk, bv,
                                        Qhi, Qlo, Khi, Vt);
    attn_kernel<<<1024, 256, 0, stream>>>(Qhi, Qlo, Khi, Vt, maskf,
                                          (float*)d_out);
}

// Round 8
// 177.965 us; speedup vs baseline: 1.8622x; 1.2536x over previous
//
#include <hip/hip_runtime.h>
#include <hip/hip_bf16.h>

#define B_ 8
#define S_ 2048
#define E_ 1024
#define D_ 64
#define VT_STRIDE 2112   // 2048 + 64: breaks 4KB channel camping

typedef short short8 __attribute__((ext_vector_type(8)));
typedef short short4v __attribute__((ext_vector_type(4)));
typedef float floatx4 __attribute__((ext_vector_type(4)));

static __device__ __forceinline__ short bf16_bits(float f) {
    __hip_bfloat16 h = __float2bfloat16(f);
    return *reinterpret_cast<short*>(&h);
}
static __device__ __forceinline__ float bits_to_f(short s) {
    __hip_bfloat16 h = *reinterpret_cast<__hip_bfloat16*>(&s);
    return __bfloat162float(h);
}
static __device__ __forceinline__ void split8(const float* __restrict__ p,
                                              short8& hi, short8& lo) {
    #pragma unroll
    for (int j = 0; j < 8; j++) {
        float f = p[j];
        short h = bf16_bits(f);
        hi[j] = h;
        lo[j] = bf16_bits(f - bits_to_f(h));
    }
}
static __device__ __forceinline__ void split8v(const float v[8],
                                               short8& hi, short8& lo) {
    #pragma unroll
    for (int j = 0; j < 8; j++) {
        float f = v[j];
        short h = bf16_bits(f);
        hi[j] = h;
        lo[j] = bf16_bits(f - bits_to_f(h));
    }
}

// ---------------- W pre-pack: fp32 W[3][64][1024] -> hi/lo bf16 B-fragments.
__global__ __launch_bounds__(256) void w_pack(
    const float* __restrict__ Wq, const float* __restrict__ Wk,
    const float* __restrict__ Wv, short8* __restrict__ Wpk8)
{
    const int t = blockIdx.x * 256 + threadIdx.x;       // 24576 total
    const int l16  = t & 15;
    const int quad = (t >> 4) & 3;
    const int nb   = (t >> 6) & 3;
    const int m    = (t >> 8) % 3;
    const int e0c  = (t >> 8) / 3;                      // 0..31
    const float* W = (m == 0) ? Wq : ((m == 1) ? Wk : Wv);
    short8 hi, lo;
    split8(W + (size_t)(nb * 16 + l16) * E_ + e0c * 32 + quad * 8, hi, lo);
    Wpk8[(size_t)t * 2]     = hi;
    Wpk8[(size_t)t * 2 + 1] = lo;
}

// ---------------- Mask prep: 3-way dtype detection (int32 / uint8 / float32)
__global__ __launch_bounds__(256) void mask_prep(const void* __restrict__ mask_raw,
                                                 float* __restrict__ maskf)
{
    __shared__ unsigned int red[256];
    const unsigned int* w = (const unsigned int*)mask_raw;
    unsigned int local = 0;
    for (int i = threadIdx.x; i < 4096; i += 256) local |= w[i];
    red[threadIdx.x] = local;
    __syncthreads();
    for (int s = 128; s > 0; s >>= 1) {
        if (threadIdx.x < s) red[threadIdx.x] |= red[threadIdx.x + s];
        __syncthreads();
    }
    const unsigned int ov = red[0];
    const bool is_u8 = (ov > 1u) && ((ov >> 24) <= 1u);
    const int i = blockIdx.x * 256 + threadIdx.x;
    int v;
    if (ov == 0u)      v = 0;
    else if (is_u8)    v = (int)((const unsigned char*)mask_raw)[i];
    else               v = (((const unsigned int*)mask_raw)[i] != 0u);
    maskf[i] = v ? -1e30f : 0.0f;
}

// ---------------- QKV: 32 rows/block, wave = one nb column-block, grid 512.
// x tile (32 rows x 32 cols fp32, 4KB) staged via global_load_lds double
// buffer, shared by all 4 waves (kills 4x redundant x loads). XOR-swizzled
// chunk placement (on the SOURCE address, DMA dest stays lane-contiguous)
// makes the strided LDS reads conflict-free.
__global__ __launch_bounds__(256, 4) void qkv_kernel(
    const float* __restrict__ x, const short8* __restrict__ Wpk8,
    const float* __restrict__ bq, const float* __restrict__ bk,
    const float* __restrict__ bv,
    short* __restrict__ Qhi, short* __restrict__ Qlo,
    short* __restrict__ Khi, short* __restrict__ Vt)
{
    __shared__ alignas(16) float xsf[2 * 1024];   // [buf][32 rows][32 cols]
    const int tid  = threadIdx.x;
    const int nb   = tid >> 6;          // wave = nb 0..3
    const int lane = tid & 63;
    const int l16  = lane & 15;
    const int quad = lane >> 4;
    const int row0 = blockIdx.x * 32;

    // DMA mapping: thread t -> LDS flat float idx t*4 = [r=t>>3][chunk k=t&7].
    // Stored chunk k holds source chunk k^(r&7)  (read-side swizzle inverse).
    const float* gdma = x + (size_t)(row0 + (tid >> 3)) * E_ +
                        (((tid & 7) ^ ((tid >> 3) & 7)) * 4);
    float* ldst_base = xsf + (size_t)(tid >> 6) * 256;   // wave-uniform

    floatx4 acc[3][2];
    #pragma unroll
    for (int m = 0; m < 3; m++)
        #pragma unroll
        for (int rt = 0; rt < 2; rt++) acc[m][rt] = (floatx4){0.f,0.f,0.f,0.f};

    const size_t lbase = (size_t)quad * 16 + l16;

    // prime buffer 0
    __builtin_amdgcn_global_load_lds(
        (const __attribute__((address_space(1))) unsigned int*)gdma,
        (__attribute__((address_space(3))) unsigned int*)ldst_base, 16, 0, 0);

    int buf = 0;
    for (int e0c = 0; e0c < 32; ++e0c) {
        __syncthreads();   // DMA for buf complete; prior reads of buf done block-wide
        if (e0c + 1 < 32)
            __builtin_amdgcn_global_load_lds(
                (const __attribute__((address_space(1))) unsigned int*)(gdma + (e0c + 1) * 32),
                (__attribute__((address_space(3))) unsigned int*)(ldst_base + (buf ^ 1) * 1024),
                16, 0, 0);

        short8 wh[3], wl[3];
        #pragma unroll
        for (int m = 0; m < 3; m++) {
            const size_t ent = ((size_t)((e0c * 3 + m) * 4 + nb) * 64 + lbase) * 2;
            wh[m] = Wpk8[ent];
            wl[m] = Wpk8[ent + 1];
        }
        short8 ah[2], al[2];
        #pragma unroll
        for (int rt = 0; rt < 2; rt++) {
            const int rr = rt * 16 + l16;
            const int rx = rr & 7;
            const float* xr = xsf + buf * 1024 + rr * 32;
            float4 a0 = *reinterpret_cast<const float4*>(xr + (((2 * quad)     ^ rx) * 4));
            float4 a1 = *reinterpret_cast<const float4*>(xr + (((2 * quad + 1) ^ rx) * 4));
            float av[8] = {a0.x, a0.y, a0.z, a0.w, a1.x, a1.y, a1.z, a1.w};
            split8v(av, ah[rt], al[rt]);
        }
        #pragma unroll
        for (int m = 0; m < 3; m++)
            #pragma unroll
            for (int rt = 0; rt < 2; rt++) {
                acc[m][rt] = __builtin_amdgcn_mfma_f32_16x16x32_bf16(al[rt], wh[m], acc[m][rt], 0, 0, 0);
                acc[m][rt] = __builtin_amdgcn_mfma_f32_16x16x32_bf16(ah[rt], wl[m], acc[m][rt], 0, 0, 0);
                acc[m][rt] = __builtin_amdgcn_mfma_f32_16x16x32_bf16(ah[rt], wh[m], acc[m][rt], 0, 0, 0);
            }
        buf ^= 1;
    }

    // epilogue: C rows = row0 + rt*16 + quad*4 + r, col d = nb*16 + l16
    const int d = nb * 16 + l16;
    const float bqv = bq[d];
    const float bkv = bk[d];
    const float bvv = bv[d];
    const int bch = row0 >> 11;
    #pragma unroll
    for (int rt = 0; rt < 2; rt++) {
        const int rowbase = row0 + rt * 16 + quad * 4;
        short4v vpk;
        #pragma unroll
        for (int r = 0; r < 4; r++) {
            const size_t row = (size_t)(rowbase + r);
            const float q = (acc[0][rt][r] + bqv) * 0.125f;
            const short qhv = bf16_bits(q);
            Qhi[row * 64 + d] = qhv;
            Qlo[row * 64 + d] = bf16_bits(q - bits_to_f(qhv));
            Khi[row * 64 + d] = bf16_bits(acc[1][rt][r] + bkv);
            vpk[r] = bf16_bits(acc[2][rt][r] + bvv);
        }
        const int s0 = (rowbase & 2047);
        *reinterpret_cast<short4v*>(Vt + ((size_t)(bch * 64 + d)) * VT_STRIDE + s0) = vpk;
    }
}

// ---------------- Flash attention (transposed): wave = 32 queries (2 groups
// of 16) sharing K AND V fragments; 4-way key split; 256 thr; grid 512.
// Two independent softmax chains per wave give in-wave ILP.
union alignas(16) AttnLds {
    short PlT[4][16][72];               // per-wave P^T round-trip (per group, reused)
    struct {
        float Osh[4][32][65];
        float msh[4][32], lsh[4][32];
    } mg;
};

__global__ __launch_bounds__(256, 2) void attn_kernel(
    const short* __restrict__ Qhi, const short* __restrict__ Qlo,
    const short* __restrict__ Khi, const short* __restrict__ Vt,
    const float* __restrict__ maskf, float* __restrict__ out)
{
    __shared__ AttnLds lds;
    const int tid  = threadIdx.x;
    const int wave = tid >> 6;          // 0..3 = key split
    const int lane = tid & 63;
    const int l16  = lane & 15;
    const int quad = lane >> 4;
    const int b    = blockIdx.x >> 6;
    const int qt   = blockIdx.x & 63;   // 64 q-tiles of 32 per batch
    const size_t qbase  = (size_t)b * S_ + qt * 32;
    const size_t kplane = (size_t)b * S_;
    const short* Vb = Vt + (size_t)b * 64 * VT_STRIDE;

    short8 qh[2][2], ql[2][2];
    #pragma unroll
    for (int g = 0; g < 2; g++)
        #pragma unroll
        for (int dc = 0; dc < 2; dc++) {
            qh[g][dc] = *reinterpret_cast<const short8*>(
                Qhi + (qbase + g * 16 + l16) * 64 + dc * 32 + quad * 8);
            ql[g][dc] = *reinterpret_cast<const short8*>(
                Qlo + (qbase + g * 16 + l16) * 64 + dc * 32 + quad * 8);
        }

    float m[2] = {-1e30f, -1e30f}, l[2] = {0.f, 0.f};
    floatx4 O[2][4];
    #pragma unroll
    for (int g = 0; g < 2; g++)
        #pragma unroll
        for (int ob = 0; ob < 4; ob++) O[g][ob] = (floatx4){0.f,0.f,0.f,0.f};

    const int kt0 = wave * 512;
    short8 kf[4][2];
    #pragma unroll
    for (int kb = 0; kb < 4; kb++)
        #pragma unroll
        for (int kc = 0; kc < 2; kc++)
            kf[kb][kc] = *reinterpret_cast<const short8*>(
                Khi + (kplane + kt0 + kb * 16 + l16) * 64 + kc * 32 + quad * 8);

    for (int t = 0; t < 8; ++t) {
        const int kt = kt0 + t * 64;

        short8 vf[4][2];
        #pragma unroll
        for (int ob = 0; ob < 4; ob++)
            #pragma unroll
            for (int kc = 0; kc < 2; kc++)
                vf[ob][kc] = *reinterpret_cast<const short8*>(
                    Vb + (size_t)(ob * 16 + l16) * VT_STRIDE + kt + kc * 32 + quad * 8);
        float4 mk4[4];
        #pragma unroll
        for (int kb = 0; kb < 4; kb++)
            mk4[kb] = *reinterpret_cast<const float4*>(
                maskf + kplane + kt + kb * 16 + quad * 4);

        // S^T = K . Q^T for both q-groups (K shared)
        floatx4 sc[2][4];
        #pragma unroll
        for (int kb = 0; kb < 4; kb++)
            #pragma unroll
            for (int g = 0; g < 2; g++) {
                floatx4 a = (floatx4){0.f,0.f,0.f,0.f};
                #pragma unroll
                for (int kc = 0; kc < 2; kc++) {
                    a = __builtin_amdgcn_mfma_f32_16x16x32_bf16(kf[kb][kc], qh[g][kc], a, 0, 0, 0);
                    a = __builtin_amdgcn_mfma_f32_16x16x32_bf16(kf[kb][kc], ql[g][kc], a, 0, 0, 0);
                }
                sc[g][kb] = a;
            }

        // refill K for next tile (issued before softmax)
        if (t < 7) {
            #pragma unroll
            for (int kb = 0; kb < 4; kb++)
                #pragma unroll
                for (int kc = 0; kc < 2; kc++)
                    kf[kb][kc] = *reinterpret_cast<const short8*>(
                        Khi + (kplane + kt + 64 + kb * 16 + l16) * 64 + kc * 32 + quad * 8);
        }

        #pragma unroll
        for (int g = 0; g < 2; g++)
            #pragma unroll
            for (int kb = 0; kb < 4; kb++) {
                const float* mkp = reinterpret_cast<const float*>(&mk4[kb]);
                #pragma unroll
                for (int r = 0; r < 4; r++) sc[g][kb][r] += mkp[r];
            }

        // online softmax: two independent chains (ILP)
        float alpha[2];
        #pragma unroll
        for (int g = 0; g < 2; g++) {
            float mx = -1e30f;
            #pragma unroll
            for (int kb = 0; kb < 4; kb++)
                #pragma unroll
                for (int r = 0; r < 4; r++) mx = fmaxf(mx, sc[g][kb][r]);
            mx = fmaxf(mx, __shfl_xor(mx, 16, 64));
            mx = fmaxf(mx, __shfl_xor(mx, 32, 64));
            const float mnew = fmaxf(fmaxf(m[g], mx), -1e29f);
            alpha[g] = __expf(m[g] - mnew);
            float ps = 0.f;
            #pragma unroll
            for (int kb = 0; kb < 4; kb++)
                #pragma unroll
                for (int r = 0; r < 4; r++) {
                    const float pe = __expf(sc[g][kb][r] - mnew);
                    sc[g][kb][r] = pe;
                    ps += pe;
                }
            ps += __shfl_xor(ps, 16, 64);
            ps += __shfl_xor(ps, 32, 64);
            l[g] = l[g] * alpha[g] + ps;
            m[g] = mnew;
            #pragma unroll
            for (int ob = 0; ob < 4; ob++) O[g][ob] *= alpha[g];
        }

        // PV per group (V shared); PlT reused sequentially, same-wave ds order
        #pragma unroll
        for (int g = 0; g < 2; g++) {
            #pragma unroll
            for (int kb = 0; kb < 4; kb++)
                #pragma unroll
                for (int r = 0; r < 4; r++)
                    lds.PlT[wave][l16][kb * 16 + quad * 4 + r] = bf16_bits(sc[g][kb][r]);
            short8 pf[2];
            #pragma unroll
            for (int kc = 0; kc < 2; kc++)
                pf[kc] = *reinterpret_cast<const short8*>(&lds.PlT[wave][l16][kc * 32 + quad * 8]);
            #pragma unroll
            for (int ob = 0; ob < 4; ob++)
                #pragma unroll
                for (int kc = 0; kc < 2; kc++)
                    O[g][ob] = __builtin_amdgcn_mfma_f32_16x16x32_bf16(vf[ob][kc], pf[kc], O[g][ob], 0, 0, 0);
        }
    }

    __syncthreads();   // union transition: all waves done with PlT
    #pragma unroll
    for (int g = 0; g < 2; g++) {
        #pragma unroll
        for (int ob = 0; ob < 4; ob++)
            #pragma unroll
            for (int r = 0; r < 4; r++)
                lds.mg.Osh[wave][g * 16 + l16][ob * 16 + quad * 4 + r] = O[g][ob][r];
        if (quad == 0) {
            lds.mg.msh[wave][g * 16 + l16] = m[g];
            lds.mg.lsh[wave][g * 16 + l16] = l[g];
        }
    }
    __syncthreads();

    // merge 4 key-splits (LSE combine); 32q x 64d = 2048 elems, 8 per thread
    #pragma unroll
    for (int part = 0; part < 8; part++) {
        const int idx = part * 256 + tid;
        const int q = idx >> 6;
        const int d = idx & 63;
        float ms = -1e30f;
        #pragma unroll
        for (int w = 0; w < 4; w++) ms = fmaxf(ms, lds.mg.msh[w][q]);
        float lt = 0.f, oa = 0.f;
        #pragma unroll
        for (int w = 0; w < 4; w++) {
            const float ww = __expf(lds.mg.msh[w][q] - ms);
            lt += lds.mg.lsh[w][q] * ww;
            oa += lds.mg.Osh[w][q][d] * ww;
        }
        out[(qbase + q) * 64 + d] = oa / lt;
    }
}

extern "C" void kernel_launch(void* const* d_in, const int* in_sizes, int n_in,
                              void* d_out, int out_size, void* d_ws, size_t ws_size,
                              hipStream_t stream) {
    const float* x  = (const float*)d_in[0];
    const float* Wq = (const float*)d_in[1];
    const float* bq = (const float*)d_in[2];
    const float* Wk = (const float*)d_in[3];
    const float* bk = (const float*)d_in[4];
    const float* Wv = (const float*)d_in[5];
    const float* bv = (const float*)d_in[6];
    const void* mask = d_in[7];

    char* ws = (char*)d_ws;
    const size_t PLANE = (size_t)B_ * S_ * D_;           // 1M shorts = 2MB
    short* Wpk = (short*)ws;                              // 768 KB
    short* Qhi = (short*)(ws + 768 * 1024);
    short* Qlo = Qhi + PLANE;
    short* Khi = Qlo + PLANE;
    short* Vt  = Khi + PLANE;                             // 512*2112 shorts
    float* maskf = (float*)(Vt + (size_t)512 * VT_STRIDE);

    w_pack<<<96, 256, 0, stream>>>(Wq, Wk, Wv, (short8*)Wpk);
    mask_prep<<<64, 256, 0, stream>>>(mask, maskf);
    qkv_kernel<<<512, 256, 0, stream>>>(x, (const short8*)Wpk, bq, bk, bv,
                                        Qhi, Qlo, Khi, Vt);
    attn_kernel<<<512, 256, 0, stream>>>(Qhi, Qlo, Khi, Vt, maskf,
                                         (float*)d_out);
}